// Round 1
// baseline (1585.959 us; speedup 1.0000x reference)
//
#include <hip/hip_runtime.h>

typedef unsigned short ushort_t;
typedef unsigned int uint32;
typedef __attribute__((ext_vector_type(8))) short short8;
typedef __attribute__((ext_vector_type(4))) float f32x4;

__device__ inline float bf2f(unsigned short u){ return __uint_as_float(((uint32)u)<<16); }
__device__ inline unsigned short f2bf(float f){
    uint32 x = __float_as_uint(f);
    x += 0x7fffu + ((x>>16)&1u);           // round-to-nearest-even
    return (unsigned short)(x>>16);
}

// ---------------- pool: pooled[b*256+c] = mean over 16384 pixels ----------------
__global__ __launch_bounds__(256) void pool_kernel(const float* __restrict__ x,
                                                   float* __restrict__ pooled){
    int bc = blockIdx.x;                    // 0..2047 = b*256+c
    const float4* row = (const float4*)(x + (size_t)bc*16384);
    float s = 0.f;
#pragma unroll
    for(int k=0;k<16;k++){ float4 v = row[threadIdx.x + k*256]; s += v.x+v.y+v.z+v.w; }
    for(int off=32; off; off>>=1) s += __shfl_down(s, off, 64);
    __shared__ float ls[4];
    int lane = threadIdx.x & 63, w = threadIdx.x >> 6;
    if(lane==0) ls[w] = s;
    __syncthreads();
    if(threadIdx.x==0) pooled[bc] = (ls[0]+ls[1]+ls[2]+ls[3]) * (1.0f/16384.0f);
}

// ---------------- head: sigmoid map -> gumbel argmax -> piror[8,256] ----------------
__global__ __launch_bounds__(256) void head_kernel(const float* __restrict__ W_map,
                                                   const float* __restrict__ proj_w,
                                                   const float* __restrict__ proj_b,
                                                   const float* __restrict__ embed,
                                                   const float* __restrict__ gu,
                                                   const float* __restrict__ pooled,
                                                   float* __restrict__ piror){
    __shared__ float m[256];
    __shared__ float lg[20];
    __shared__ int sidx;
    int t = threadIdx.x;
    for(int b=0;b<8;b++){
        float s = 0.f;
        const float* wr = W_map + (size_t)t*256;
        const float* pb = pooled + b*256;
        for(int c=0;c<256;c++) s += wr[c]*pb[c];
        m[t] = 1.0f/(1.0f+__expf(-s));
        __syncthreads();
        if(t<20){
            float s2 = 0.f;
            const float* pw = proj_w + (size_t)t*256;
            for(int c=0;c<256;c++) s2 += pw[c]*m[c];
            float u = gu[b*20+t];
            float g = -logf(-logf(u + 1e-10f) + 1e-10f);
            lg[t] = s2 + proj_b[t] + g;       // TAU=1; softmax is monotone -> argmax of this
        }
        __syncthreads();
        if(t==0){
            int best = 0; float bv = lg[0];
            for(int n=1;n<20;n++) if(lg[n] > bv){ bv = lg[n]; best = n; }
            sidx = best;
        }
        __syncthreads();
        piror[b*256+t] = embed[(size_t)sidx*256 + t];
        __syncthreads();
    }
}

// ---------------- pack: NCHW fp32 -> NHWC bf16, + piror ----------------
__global__ __launch_bounds__(256) void pack_kernel(const float* __restrict__ x,
                                                   const float* __restrict__ piror,
                                                   unsigned short* __restrict__ h){
    __shared__ float tile[64][65];
    int bx = blockIdx.x;            // 8192 blocks
    int b    =  bx >> 10;
    int cblk = (bx >> 8) & 3;
    int pblk =  bx & 255;
    int c0 = cblk*64, p0 = pblk*64;
    int col = threadIdx.x & 63;
    int r0  = threadIdx.x >> 6;
    const float* xb = x + ((size_t)(b*256 + c0))*16384 + p0;
#pragma unroll
    for(int it=0; it<16; it++){
        int r = r0 + it*4;
        tile[r][col] = xb[(size_t)r*16384 + col];
    }
    __syncthreads();
    float pir = piror[b*256 + c0 + col];
    unsigned short* hb = h + ((size_t)(b*16384 + p0))*256 + c0;
#pragma unroll
    for(int it=0; it<16; it++){
        int p = r0 + it*4;
        hb[(size_t)p*256 + col] = f2bf(tile[col][p] + pir);
    }
}

// ---------------- wtrans: res_w [cv][o][i][tap] fp32 -> wT [cv][tap][o][c] bf16 ----------------
__global__ __launch_bounds__(256) void wtrans_kernel(const float* __restrict__ w1,
                                                     const float* __restrict__ w2,
                                                     unsigned short* __restrict__ wT){
    int bx = blockIdx.x;            // (cv*9+tap)*256 + o ; 13824 blocks
    int o  = bx & 255;
    int tt = bx >> 8;               // 0..53
    int cv = tt / 9, tap = tt % 9;
    int res = cv >> 1;
    const float* src = ((cv & 1) ? w2 : w1) + (size_t)res * 589824;  // 256*256*9
    int c = threadIdx.x;
    float v = src[((size_t)o*256 + c)*9 + tap];
    wT[(size_t)bx*256 + c] = f2bf(v);
}

// ---------------- conv: implicit GEMM, 128 och x 128 pixels, K = 9*256 ----------------
// MODE 0: conv1: relu(acc+bias) -> dst (bf16 NHWC)
// MODE 1: conv2: acc+bias+skip  -> dst (bf16 NHWC, in-place h)
// MODE 2: conv2 final: acc+bias+skip -> out (fp32 NCHW)
template<int MODE>
__global__ __launch_bounds__(256, 2)
void conv_kernel(const unsigned short* __restrict__ src,
                 const unsigned short* __restrict__ wTc,
                 const float* __restrict__ bias,
                 unsigned short* __restrict__ dst,
                 const unsigned short* __restrict__ hskip,
                 float* __restrict__ out,
                 const unsigned short* __restrict__ zp){
    __shared__ unsigned short ldsW[128*32];   // [o_local][c32]   8 KB
    __shared__ unsigned short ldsX[128*32];   // [pixel][c32]     8 KB
    int tid = threadIdx.x;
    int bid = blockIdx.x;
    int pt   = bid >> 1;             // 0..1023 = b*128 + y   (pixel tile = full W row)
    int och0 = (bid & 1) * 128;
    int b = pt >> 7, y = pt & 127;

    int lane = tid & 63;
    int wid  = tid >> 6;
    int wm = wid >> 1, wn = wid & 1;
    int l15 = lane & 15, quad = lane >> 4;

    f32x4 acc[4][4];
#pragma unroll
    for(int i=0;i<4;i++)
#pragma unroll
        for(int j=0;j<4;j++){ f32x4 z = {0.f,0.f,0.f,0.f}; acc[i][j] = z; }

    for(int ks=0; ks<72; ks++){
        int tap = ks >> 3, cc = ks & 7;
        int dy = tap/3 - 1, dx = tap%3 - 1;
        __syncthreads();
        // stage X: 128 pixels x 32 ch  (512 chunks of 16B; 2 per thread)
#pragma unroll
        for(int rr=0; rr<2; rr++){
            int q = tid + rr*256;
            int p = q >> 2, part = q & 3;
            int xx = p + dx, yy = y + dy;
            const unsigned short* g;
            if((unsigned)xx < 128u && (unsigned)yy < 128u)
                g = src + ((size_t)((b*128+yy)*128 + xx))*256 + cc*32 + part*8;
            else
                g = zp + part*8;   // zero page: padding
            __builtin_amdgcn_global_load_lds(
                (const __attribute__((address_space(1))) void*)g,
                (__attribute__((address_space(3))) void*)&ldsX[(wid*64 + rr*256)*8],
                16, 0, 0);
        }
        // stage W: 128 och x 32 ch
#pragma unroll
        for(int rr=0; rr<2; rr++){
            int q = tid + rr*256;
            int r = q >> 2, part = q & 3;
            const unsigned short* g = wTc + ((size_t)(tap*256 + och0 + r))*256 + cc*32 + part*8;
            __builtin_amdgcn_global_load_lds(
                (const __attribute__((address_space(1))) void*)g,
                (__attribute__((address_space(3))) void*)&ldsW[(wid*64 + rr*256)*8],
                16, 0, 0);
        }
        __syncthreads();

        short8 av[4], bv[4];
#pragma unroll
        for(int i=0;i<4;i++) av[i] = *(const short8*)&ldsW[(wm*64 + i*16 + l15)*32 + quad*8];
#pragma unroll
        for(int j=0;j<4;j++) bv[j] = *(const short8*)&ldsX[(wn*64 + j*16 + l15)*32 + quad*8];
#pragma unroll
        for(int i=0;i<4;i++)
#pragma unroll
            for(int j=0;j<4;j++)
                acc[i][j] = __builtin_amdgcn_mfma_f32_16x16x32_bf16(av[i], bv[j], acc[i][j], 0,0,0);
    }

    // epilogue: C/D layout col(n=pixel)=lane&15, row(m=och)=quad*4+reg
    size_t gprow = (size_t)pt*128;
#pragma unroll
    for(int i=0;i<4;i++){
        int olocal = wm*64 + i*16 + quad*4;
        int o = och0 + olocal;
        float4 bb = *(const float4*)&bias[o];
        float bias4[4] = {bb.x, bb.y, bb.z, bb.w};
#pragma unroll
        for(int j=0;j<4;j++){
            int p = wn*64 + j*16 + l15;
            size_t gpix = gprow + p;
            float v[4];
#pragma unroll
            for(int r=0;r<4;r++) v[r] = acc[i][j][r] + bias4[r];
            if(MODE==0){
#pragma unroll
                for(int r=0;r<4;r++) v[r] = fmaxf(v[r], 0.0f);
                ushort4 st; st.x=f2bf(v[0]); st.y=f2bf(v[1]); st.z=f2bf(v[2]); st.w=f2bf(v[3]);
                *(ushort4*)&dst[gpix*256 + o] = st;
            } else {
                ushort4 sk = *(const ushort4*)&hskip[gpix*256 + o];
                v[0]+=bf2f(sk.x); v[1]+=bf2f(sk.y); v[2]+=bf2f(sk.z); v[3]+=bf2f(sk.w);
                if(MODE==1){
                    ushort4 st; st.x=f2bf(v[0]); st.y=f2bf(v[1]); st.z=f2bf(v[2]); st.w=f2bf(v[3]);
                    *(ushort4*)&dst[gpix*256 + o] = st;
                } else {
                    size_t outbase = ((size_t)(b*256 + o))*16384 + (size_t)y*128 + p;
#pragma unroll
                    for(int r=0;r<4;r++) out[outbase + (size_t)r*16384] = v[r];
                }
            }
        }
    }
}

// ---------------- launch ----------------
extern "C" void kernel_launch(void* const* d_in, const int* in_sizes, int n_in,
                              void* d_out, int out_size, void* d_ws, size_t ws_size,
                              hipStream_t stream){
    const float* x      = (const float*)d_in[0];
    const float* gu     = (const float*)d_in[1];
    const float* W_map  = (const float*)d_in[2];
    const float* proj_w = (const float*)d_in[3];
    const float* proj_b = (const float*)d_in[4];
    const float* embed  = (const float*)d_in[5];
    const float* rw1    = (const float*)d_in[6];
    const float* rb1    = (const float*)d_in[7];
    const float* rw2    = (const float*)d_in[8];
    const float* rb2    = (const float*)d_in[9];
    float* out = (float*)d_out;

    char* ws = (char*)d_ws;
    unsigned short* zp     = (unsigned short*)(ws + 0);        // 256 B zero page
    float*          pooled = (float*)(ws + 4096);              // 8 KB
    float*          piror  = (float*)(ws + 16384);             // 8 KB
    unsigned short* wT     = (unsigned short*)(ws + 32768);    // 6*9*256*256*2 = 6.75 MB
    unsigned short* hbuf   = (unsigned short*)(ws + ((size_t)8<<20));                    // 64 MB
    unsigned short* tbuf   = (unsigned short*)(ws + ((size_t)8<<20) + ((size_t)64<<20)); // 64 MB

    hipMemsetAsync(zp, 0, 256, stream);
    pool_kernel<<<2048, 256, 0, stream>>>(x, pooled);
    head_kernel<<<1, 256, 0, stream>>>(W_map, proj_w, proj_b, embed, gu, pooled, piror);
    pack_kernel<<<8192, 256, 0, stream>>>(x, piror, hbuf);
    wtrans_kernel<<<13824, 256, 0, stream>>>(rw1, rw2, wT);

    for(int res=0; res<3; res++){
        const unsigned short* w1c = wT + (size_t)(res*2+0)*9*256*256;
        const unsigned short* w2c = wT + (size_t)(res*2+1)*9*256*256;
        conv_kernel<0><<<2048, 256, 0, stream>>>(hbuf, w1c, rb1 + res*256, tbuf, nullptr, nullptr, zp);
        if(res < 2)
            conv_kernel<1><<<2048, 256, 0, stream>>>(tbuf, w2c, rb2 + res*256, hbuf, hbuf, nullptr, zp);
        else
            conv_kernel<2><<<2048, 256, 0, stream>>>(tbuf, w2c, rb2 + res*256, nullptr, hbuf, out, zp);
    }
}

// Round 2
// 1241.053 us; speedup vs baseline: 1.2779x; 1.2779x over previous
//
#include <hip/hip_runtime.h>

typedef unsigned int uint32;
typedef __attribute__((ext_vector_type(8))) short short8;
typedef __attribute__((ext_vector_type(4))) float f32x4;

__device__ inline float bf2f(unsigned short u){ return __uint_as_float(((uint32)u)<<16); }
__device__ inline unsigned short f2bf(float f){
    uint32 x = __float_as_uint(f);
    x += 0x7fffu + ((x>>16)&1u);           // round-to-nearest-even
    return (unsigned short)(x>>16);
}

// ---------------- pool: pooled[b*256+c] = mean over 16384 pixels ----------------
__global__ __launch_bounds__(256) void pool_kernel(const float* __restrict__ x,
                                                   float* __restrict__ pooled){
    int bc = blockIdx.x;                    // 0..2047 = b*256+c
    const float4* row = (const float4*)(x + (size_t)bc*16384);
    float s = 0.f;
#pragma unroll
    for(int k=0;k<16;k++){ float4 v = row[threadIdx.x + k*256]; s += v.x+v.y+v.z+v.w; }
    for(int off=32; off; off>>=1) s += __shfl_down(s, off, 64);
    __shared__ float ls[4];
    int lane = threadIdx.x & 63, w = threadIdx.x >> 6;
    if(lane==0) ls[w] = s;
    __syncthreads();
    if(threadIdx.x==0) pooled[bc] = (ls[0]+ls[1]+ls[2]+ls[3]) * (1.0f/16384.0f);
}

// ---------------- head: sigmoid map -> gumbel argmax -> piror[8,256] ----------------
__global__ __launch_bounds__(256) void head_kernel(const float* __restrict__ W_map,
                                                   const float* __restrict__ proj_w,
                                                   const float* __restrict__ proj_b,
                                                   const float* __restrict__ embed,
                                                   const float* __restrict__ gu,
                                                   const float* __restrict__ pooled,
                                                   float* __restrict__ piror){
    __shared__ float m[256];
    __shared__ float lg[20];
    __shared__ int sidx;
    int t = threadIdx.x;
    for(int b=0;b<8;b++){
        float s = 0.f;
        const float* wr = W_map + (size_t)t*256;
        const float* pb = pooled + b*256;
        for(int c=0;c<256;c++) s += wr[c]*pb[c];
        m[t] = 1.0f/(1.0f+__expf(-s));
        __syncthreads();
        if(t<20){
            float s2 = 0.f;
            const float* pw = proj_w + (size_t)t*256;
            for(int c=0;c<256;c++) s2 += pw[c]*m[c];
            float u = gu[b*20+t];
            float g = -logf(-logf(u + 1e-10f) + 1e-10f);
            lg[t] = s2 + proj_b[t] + g;       // TAU=1; softmax is monotone -> argmax of this
        }
        __syncthreads();
        if(t==0){
            int best = 0; float bv = lg[0];
            for(int n=1;n<20;n++) if(lg[n] > bv){ bv = lg[n]; best = n; }
            sidx = best;
        }
        __syncthreads();
        piror[b*256+t] = embed[(size_t)sidx*256 + t];
        __syncthreads();
    }
}

// ---------------- pack: NCHW fp32 -> NHWC bf16, + piror ----------------
__global__ __launch_bounds__(256) void pack_kernel(const float* __restrict__ x,
                                                   const float* __restrict__ piror,
                                                   unsigned short* __restrict__ h){
    __shared__ float tile[64][65];
    int bx = blockIdx.x;            // 8192 blocks
    int b    =  bx >> 10;
    int cblk = (bx >> 8) & 3;
    int pblk =  bx & 255;
    int c0 = cblk*64, p0 = pblk*64;
    int col = threadIdx.x & 63;
    int r0  = threadIdx.x >> 6;
    const float* xb = x + ((size_t)(b*256 + c0))*16384 + p0;
#pragma unroll
    for(int it=0; it<16; it++){
        int r = r0 + it*4;
        tile[r][col] = xb[(size_t)r*16384 + col];
    }
    __syncthreads();
    float pir = piror[b*256 + c0 + col];
    unsigned short* hb = h + ((size_t)(b*16384 + p0))*256 + c0;
#pragma unroll
    for(int it=0; it<16; it++){
        int p = r0 + it*4;
        hb[(size_t)p*256 + col] = f2bf(tile[col][p] + pir);
    }
}

// ---------------- wtrans: res_w [cv][o][i][tap] fp32 -> wT [cv][tap][o][c] bf16 ----------------
__global__ __launch_bounds__(256) void wtrans_kernel(const float* __restrict__ w1,
                                                     const float* __restrict__ w2,
                                                     unsigned short* __restrict__ wT){
    int bx = blockIdx.x;            // (cv*9+tap)*256 + o ; 13824 blocks
    int o  = bx & 255;
    int tt = bx >> 8;               // 0..53
    int cv = tt / 9, tap = tt % 9;
    int res = cv >> 1;
    const float* src = ((cv & 1) ? w2 : w1) + (size_t)res * 589824;  // 256*256*9
    int c = threadIdx.x;
    float v = src[((size_t)o*256 + c)*9 + tap];
    wT[(size_t)bx*256 + c] = f2bf(v);
}

// ---------------- conv: implicit GEMM, 256 och x 128 px (1 row), tap-reuse K-loop ----------------
// K-loop: cc (8 chunks of 32 ch) outer; stage 3 halo'd rows of X once per cc; 9 taps inner
// off the same X staging, weights double-buffered and prefetched one tap ahead.
// MODE 0: conv1: relu(acc+bias) -> dst (bf16 NHWC)
// MODE 1: conv2: acc+bias+skip  -> dst (bf16 NHWC)
// MODE 2: conv2 final: acc+bias+skip -> out (fp32 NCHW)
template<int MODE>
__global__ __launch_bounds__(256, 2)
void conv_kernel(const unsigned short* __restrict__ src,
                 const unsigned short* __restrict__ wTc,
                 const float* __restrict__ bias,
                 unsigned short* __restrict__ dst,
                 const unsigned short* __restrict__ hskip,
                 float* __restrict__ out,
                 const unsigned short* __restrict__ zp){
    // X: 3 rows x 130 slots (slot s = pixel s-1; slots 0,129 = always-zero border) x 32 ch
    __shared__ unsigned short ldsX[3*4160];      // 24,960 B (row stride 4160 shorts = 8320 B)
    __shared__ unsigned short ldsW[2][256*32];   // W dbuf: 256 och x 32 ch, 16 KB each
    int tid  = threadIdx.x;
    int bid  = blockIdx.x;          // 1024 = 8 images x 128 rows
    int b    = bid & 7;             // XCD k owns image k (bid%8 dispatch heuristic)
    int y    = bid >> 3;
    int pt   = b*128 + y;

    int lane = tid & 63, wid = tid >> 6;
    int l15  = lane & 15, quad = lane >> 4;

    // zero the 6 halo slots once (never overwritten by staging)
    if(tid < 96){
        int r = tid >> 5, side = (tid >> 4) & 1, dw = tid & 15;
        ((int*)ldsX)[r*2080 + (side ? 129*16 : 0) + dw] = 0;
    }

    // --- precompute per-thread staging sources (cc/tap terms added in-loop) ---
    // X: 1536 16B-chunks per cc -> 6 per thread. chunk q: row=q>>9, pixel=(q&511)>>2, part=q&3
    // XOR-swizzle: LDS slot s keeps source part (k ^ (s&3)) at sub-slot k.
    const unsigned short* xbase[6];
    int xdst[6];
#pragma unroll
    for(int t=0;t<6;t++){
        int qb = t*256 + wid*64;
        int rb = qb >> 9;
        int cb = qb & 511;
        int q  = qb + lane;
        int p  = (q & 511) >> 2;
        int k  = q & 3;
        int kk = k ^ ((p+1)&3);
        int yy = y + rb - 1;
        xbase[t] = ((unsigned)yy < 128u)
                 ? src + ((size_t)((b*128+yy)*128 + p))*256 + kk*8
                 : zp + kk*8;                 // zp: >=1KB zeros (cc*32 added later stays in range)
        xdst[t] = rb*4160 + 32 + cb*8;        // interior starts at slot 1
    }
    // W: 1024 chunks per (tap,cc) -> 4 per thread. chunk q: och=q>>2, part=q&3, key=och&3
    const unsigned short* wbase[4];
    int wdst[4];
#pragma unroll
    for(int t=0;t<4;t++){
        int qb = t*256 + wid*64;
        int q  = qb + lane;
        int o  = q >> 2;
        int kk = (q & 3) ^ (o & 3);
        wbase[t] = wTc + ((size_t)o)*256 + kk*8;
        wdst[t]  = qb*8;
    }
    // A-fragment read offsets (och side), swizzled
    int aoff[4];
#pragma unroll
    for(int i=0;i<4;i++){
        int o = wid*64 + i*16 + l15;
        aoff[i] = o*32 + ((quad ^ (o&3))*8);
    }

    f32x4 acc[4][8];
#pragma unroll
    for(int i=0;i<4;i++)
#pragma unroll
        for(int j=0;j<8;j++){ f32x4 z = {0.f,0.f,0.f,0.f}; acc[i][j] = z; }

    for(int cc=0; cc<8; cc++){
        // stage X for this channel chunk (reused by all 9 taps)
#pragma unroll
        for(int t=0;t<6;t++)
            __builtin_amdgcn_global_load_lds(
                (const __attribute__((address_space(1))) void*)(xbase[t] + cc*32),
                (__attribute__((address_space(3))) void*)&ldsX[xdst[t]], 16, 0, 0);
        // stage W[tap=0] into buf 0
#pragma unroll
        for(int t=0;t<4;t++)
            __builtin_amdgcn_global_load_lds(
                (const __attribute__((address_space(1))) void*)(wbase[t] + cc*32),
                (__attribute__((address_space(3))) void*)&ldsW[0][wdst[t]], 16, 0, 0);
        __syncthreads();

        for(int tap=0; tap<9; tap++){
            int d = tap & 1;
            if(tap < 8){
                // prefetch next tap's weights into the other buffer; they fly during compute
#pragma unroll
                for(int t=0;t<4;t++)
                    __builtin_amdgcn_global_load_lds(
                        (const __attribute__((address_space(1))) void*)(wbase[t] + (size_t)(tap+1)*65536 + cc*32),
                        (__attribute__((address_space(3))) void*)&ldsW[d^1][wdst[t]], 16, 0, 0);
            }
            int rr = tap / 3;          // input row (0..2)
            int dx = tap % 3 - 1;      // column shift

            short8 av[4], bv[8];
#pragma unroll
            for(int i=0;i<4;i++) av[i] = *(const short8*)&ldsW[d][aoff[i]];
#pragma unroll
            for(int j=0;j<8;j++){
                int s = j*16 + l15 + dx + 1;   // slot 0..129
                bv[j] = *(const short8*)&ldsX[rr*4160 + s*32 + ((quad ^ (s&3))*8)];
            }
#pragma unroll
            for(int i=0;i<4;i++)
#pragma unroll
                for(int j=0;j<8;j++)
                    acc[i][j] = __builtin_amdgcn_mfma_f32_16x16x32_bf16(av[i], bv[j], acc[i][j], 0,0,0);
            __syncthreads();
        }
    }

    // epilogue: C/D layout col(n=pixel)=lane&15, row(m=och)=quad*4+reg
    size_t gprow = (size_t)pt*128;
#pragma unroll
    for(int i=0;i<4;i++){
        int o = wid*64 + i*16 + quad*4;
        float4 bb = *(const float4*)&bias[o];
        float bias4[4] = {bb.x, bb.y, bb.z, bb.w};
#pragma unroll
        for(int j=0;j<8;j++){
            int p = j*16 + l15;
            size_t gpix = gprow + p;
            float v[4];
#pragma unroll
            for(int r=0;r<4;r++) v[r] = acc[i][j][r] + bias4[r];
            if(MODE==0){
#pragma unroll
                for(int r=0;r<4;r++) v[r] = fmaxf(v[r], 0.0f);
                ushort4 st; st.x=f2bf(v[0]); st.y=f2bf(v[1]); st.z=f2bf(v[2]); st.w=f2bf(v[3]);
                *(ushort4*)&dst[gpix*256 + o] = st;
            } else {
                ushort4 sk = *(const ushort4*)&hskip[gpix*256 + o];
                v[0]+=bf2f(sk.x); v[1]+=bf2f(sk.y); v[2]+=bf2f(sk.z); v[3]+=bf2f(sk.w);
                if(MODE==1){
                    ushort4 st; st.x=f2bf(v[0]); st.y=f2bf(v[1]); st.z=f2bf(v[2]); st.w=f2bf(v[3]);
                    *(ushort4*)&dst[gpix*256 + o] = st;
                } else {
                    size_t outbase = ((size_t)(b*256 + o))*16384 + (size_t)y*128 + p;
#pragma unroll
                    for(int r=0;r<4;r++) out[outbase + (size_t)r*16384] = v[r];
                }
            }
        }
    }
}

// ---------------- launch ----------------
extern "C" void kernel_launch(void* const* d_in, const int* in_sizes, int n_in,
                              void* d_out, int out_size, void* d_ws, size_t ws_size,
                              hipStream_t stream){
    const float* x      = (const float*)d_in[0];
    const float* gu     = (const float*)d_in[1];
    const float* W_map  = (const float*)d_in[2];
    const float* proj_w = (const float*)d_in[3];
    const float* proj_b = (const float*)d_in[4];
    const float* embed  = (const float*)d_in[5];
    const float* rw1    = (const float*)d_in[6];
    const float* rb1    = (const float*)d_in[7];
    const float* rw2    = (const float*)d_in[8];
    const float* rb2    = (const float*)d_in[9];
    float* out = (float*)d_out;

    char* ws = (char*)d_ws;
    unsigned short* zp     = (unsigned short*)(ws + 0);        // 1 KB zero page
    float*          pooled = (float*)(ws + 4096);              // 8 KB
    float*          piror  = (float*)(ws + 16384);             // 8 KB
    unsigned short* wT     = (unsigned short*)(ws + 32768);    // 6*9*256*256*2 = 6.75 MB
    unsigned short* hbuf   = (unsigned short*)(ws + ((size_t)8<<20));                    // 64 MB
    unsigned short* tbuf   = (unsigned short*)(ws + ((size_t)8<<20) + ((size_t)64<<20)); // 64 MB

    hipMemsetAsync(zp, 0, 1024, stream);
    pool_kernel<<<2048, 256, 0, stream>>>(x, pooled);
    head_kernel<<<1, 256, 0, stream>>>(W_map, proj_w, proj_b, embed, gu, pooled, piror);
    pack_kernel<<<8192, 256, 0, stream>>>(x, piror, hbuf);
    wtrans_kernel<<<13824, 256, 0, stream>>>(rw1, rw2, wT);

    for(int res=0; res<3; res++){
        const unsigned short* w1c = wT + (size_t)(res*2+0)*9*65536;
        const unsigned short* w2c = wT + (size_t)(res*2+1)*9*65536;
        conv_kernel<0><<<1024, 256, 0, stream>>>(hbuf, w1c, rb1 + res*256, tbuf, nullptr, nullptr, zp);
        if(res < 2)
            conv_kernel<1><<<1024, 256, 0, stream>>>(tbuf, w2c, rb2 + res*256, hbuf, hbuf, nullptr, zp);
        else
            conv_kernel<2><<<1024, 256, 0, stream>>>(tbuf, w2c, rb2 + res*256, nullptr, hbuf, out, zp);
    }
}